// Round 8
// baseline (364.900 us; speedup 1.0000x reference)
//
#include <hip/hip_runtime.h>

// ConvLSTM2D MI355X, R8: 16x16 px tiles (half the weight re-fetch of R3/R7),
// wave = 64 px x 64 co (m=4), weights via global_load_lds 2-buffer slab with
// 2-barrier intervals. Theory: per-step cost dominated by L3 weight re-fetch
// (L2 dies at every kernel boundary) proportional to #px-tiles.
// B=8,T=10,H=W=64,CIN=32,F=64,4F=256,G=4.
// grid 256 = [b 8][tile 16][fh 2], 512 thr = 8 waves (pxq 4 x wq 2).
// Block = 256 px (16x16) x 128 co. K chunks: 9 X + 9 H-even + 9 H-odd
// (H halo staged in two kb-phases; X region reused for H-odd after chunk 8).

typedef __attribute__((ext_vector_type(8))) short short8v;
typedef __attribute__((ext_vector_type(4))) float f32x4;
typedef unsigned short u16;
typedef unsigned int u32;

__device__ __forceinline__ u16 f2bf(float x) {
    union { float f; unsigned u; } a; a.f = x;
    unsigned r = a.u + 0x7FFFu + ((a.u >> 16) & 1u);   // RNE
    return (u16)(r >> 16);
}
__device__ __forceinline__ float bf2f(u16 v) {
    union { unsigned u; float f; } a; a.u = ((unsigned)v) << 16; return a.f;
}
__device__ __forceinline__ float sigf(float x) { return 1.0f / (1.0f + __expf(-x)); }
__device__ __forceinline__ float tanhf_(float x) {
    float e = __expf(2.0f * x);
    return 1.0f - 2.0f / (e + 1.0f);
}

// ---- prep: x f32 -> bf16 ----
__global__ __launch_bounds__(256)
void prep_x(const float* __restrict__ x, u16* __restrict__ xb) {
    size_t i = (size_t)blockIdx.x * 256 + threadIdx.x;
    for (; i < 2621440u; i += (size_t)2048 * 256) {
        float4 v = ((const float4*)x)[i];
        union { u16 u[4]; uint2 q; } o;
        o.u[0] = f2bf(v.x); o.u[1] = f2bf(v.y);
        o.u[2] = f2bf(v.z); o.u[3] = f2bf(v.w);
        ((uint2*)xb)[i] = o.q;
    }
}

// ---- prep: weights -> staged layout (same as R7) ----
// wt_in[c9][kb4][fh2][n4][fi32][8i], wt_rk[g4][cc18][kb4][fh2][n4][fi32][8i]
__global__ __launch_bounds__(256)
void prep_w(const float* __restrict__ kern, const float* __restrict__ rk,
            u16* __restrict__ wt_in, u16* __restrict__ wt_rk) {
    int idx = blockIdx.x * 256 + threadIdx.x;
    if (idx >= 82944) return;
    const float* s;
    u16* dst;
    if (idx < 9216) {
        int fi = idx & 31, r1 = idx >> 5;
        int n = r1 & 3, r2 = r1 >> 2;
        int fh = r2 & 1, r3 = r2 >> 1;
        int kb = r3 & 3, tap = r3 >> 2;
        int co = (n << 6) + (fh << 5) + fi;
        s = kern + (size_t)((tap << 5) + (kb << 3)) * 256 + co;
        dst = wt_in + (size_t)idx * 8;
    } else {
        int j = idx - 9216;
        int fi = j & 31, r1 = j >> 5;
        int n = r1 & 3, r2 = r1 >> 2;
        int fh = r2 & 1, r3 = r2 >> 1;
        int kb = r3 & 3, r4 = r3 >> 2;           // 0..71 = g*18+cc
        int g = r4 / 18, cc = r4 - g * 18;
        int tap = cc >> 1;
        int cib = (cc & 1) << 5;
        int co = (n << 6) + (fh << 5) + fi;
        s = rk + (size_t)(((g * 9 + tap) << 6) + cib + (kb << 3)) * 256 + co;
        dst = wt_rk + (size_t)j * 8;
    }
    union { u16 u[8]; uint4 q; } o;
    #pragma unroll
    for (int i = 0; i < 8; ++i) o.u[i] = f2bf(s[i * 256]);
    *(uint4*)dst = o.q;
}

#define AS1U(p) ((const __attribute__((address_space(1))) u32*)(p))
#define AS3U(p) ((__attribute__((address_space(3))) u32*)(p))

// ---- fused conv + gates, one timestep ----
__global__ __launch_bounds__(512, 2)
void lstm_step(const u16* __restrict__ xb, const u16* __restrict__ wt_in,
               const u16* __restrict__ wt_rk, const float* __restrict__ bias,
               const int* __restrict__ labels, const u16* __restrict__ hrd,
               u16* __restrict__ hwr, float* __restrict__ cst,
               float* __restrict__ out, int t)
{
    // R0 (X halo / H-odd) @0 [kb4][324][8]; R1 (H-even) @10368; wbuf 2x4096 @20736
    __shared__ short hal[20736 + 8192];   // 57,856 B

    const int tid  = threadIdx.x;
    const int lane = tid & 63;
    const int w    = tid >> 6;
    const int pxq  = w >> 1;                  // 0..3 : 4-row band
    const int wq   = w & 1;                   // 0..1 : 16-f slice
    const int bid  = blockIdx.x;
    const int fh   = bid & 1;
    const int tile = (bid >> 1) & 15;
    const int b    = bid >> 5;
    const int y0 = (tile >> 2) << 4, x0 = (tile & 3) << 4;
    const int g = labels[b];

    const int co_l = lane & 15;
    const int kbl  = lane >> 4;
    const int prow = (lane & 15) >> 3, pcol = lane & 7;
    const int fi = (wq << 4) + co_l;          // 0..31
    const int f  = (fh << 5) + fi;            // 0..63

    float bv[4];
    #pragma unroll
    for (int n = 0; n < 4; ++n)
        bv[n] = bias[(g << 8) + (n << 6) + f];

    // A-frag base positions: frag mf = (rowpair mf>>1, colhalf mf&1), 18-wide halo
    int aoffm[4];
    #pragma unroll
    for (int mf = 0; mf < 4; ++mf)
        aoffm[mf] = ((pxq << 2) + ((mf >> 1) << 1) + prow) * 18 + ((mf & 1) << 3) + pcol;

    // ---- c prefetch + output offsets (16 px per thread) ----
    float* cb = cst + ((size_t)b << 18);
    int coff[4][4];
    float cpre[4][4];
    #pragma unroll
    for (int mf = 0; mf < 4; ++mf)
        #pragma unroll
        for (int rr = 0; rr < 4; ++rr) {
            int pf = (kbl << 2) + rr;         // 0..15 within frag (2x8)
            int yy = y0 + (pxq << 2) + ((mf >> 1) << 1) + (pf >> 3);
            int xx = x0 + ((mf & 1) << 3) + (pf & 7);
            coff[mf][rr] = (((yy << 6) + xx) << 6) + f;
            cpre[mf][rr] = (t > 0) ? cb[coff[mf][rr]] : 0.0f;
        }

    // ---- stage X halo (R0) ----
    {
        const u16* src = xb + ((size_t)(b * 10 + t) << 17);
        for (int s = tid; s < 1296; s += 512) {
            int pos = s >> 2, kb = s & 3;
            int hy = pos / 18, hx = pos - hy * 18;
            int gy = y0 + hy - 1, gx = x0 + hx - 1;
            short8v v = (short8v){0,0,0,0,0,0,0,0};
            if ((unsigned)gy < 64u && (unsigned)gx < 64u)
                v = *(const short8v*)&src[(((gy << 6) + gx) << 5) + (kb << 3)];
            *(short8v*)&hal[kb * 2592 + pos * 8] = v;
        }
    }
    // ---- stage H-even halo (R1, h-ch 0..31) ----
    if (t > 0) {
        const u16* src = hrd + ((size_t)b << 18);
        for (int s = tid; s < 1296; s += 512) {
            int pos = s >> 2, kb = s & 3;
            int hy = pos / 18, hx = pos - hy * 18;
            int gy = y0 + hy - 1, gx = x0 + hx - 1;
            short8v v = (short8v){0,0,0,0,0,0,0,0};
            if ((unsigned)gy < 64u && (unsigned)gx < 64u)
                v = *(const short8v*)&src[(((gy << 6) + gx) << 6) + (kb << 3)];
            *(short8v*)&hal[10368 + kb * 2592 + pos * 8] = v;
        }
    }

    // weight slab stage: 4096 shorts per (chunk, fh); thread stages 16B
    const int skb  = tid >> 7;
    const int srem = tid & 127;
    auto issue_stage = [&](int c, int buf) {
        const u16* gsrc;
        if (c < 9)
            gsrc = wt_in + (size_t)((((c << 2) + skb) << 1) + fh) * 1024 + (srem << 3);
        else {
            int cc = (c < 18) ? ((c - 9) << 1) : (((c - 18) << 1) + 1);
            gsrc = wt_rk + (size_t)(((((g * 18 + cc) << 2) + skb) << 1) + fh) * 1024 + (srem << 3);
        }
        __builtin_amdgcn_global_load_lds(AS1U(gsrc),
                                         AS3U(&hal[20736 + buf * 4096 + tid * 8]),
                                         16, 0, 0);
    };

    f32x4 acc[4][4];
    #pragma unroll
    for (int n = 0; n < 4; ++n)
        #pragma unroll
        for (int mf = 0; mf < 4; ++mf)
            acc[mf][n] = (f32x4){bv[n], bv[n], bv[n], bv[n]};

    const int nck = t ? 27 : 9;

    issue_stage(0, 0);
    asm volatile("s_waitcnt lgkmcnt(0) vmcnt(0)" ::: "memory");
    __builtin_amdgcn_sched_barrier(0);
    __builtin_amdgcn_s_barrier();             // halos + slab(0) staged
    __builtin_amdgcn_sched_barrier(0);

    #pragma unroll 1
    for (int c = 0; c < nck; ++c) {
        // a: ds_reads of chunk c
        int tap, abase;
        if (c < 9)       { tap = c;      abase = kbl * 2592; }
        else if (c < 18) { tap = c - 9;  abase = 10368 + kbl * 2592; }
        else             { tap = c - 18; abase = kbl * 2592; }
        const int koff = (tap / 3) * 18 + (tap % 3);
        const short* wb = &hal[20736 + (c & 1) * 4096 + kbl * 1024 + fi * 8];
        short8v bfr[4], af[4];
        #pragma unroll
        for (int n = 0; n < 4; ++n)
            bfr[n] = *(const short8v*)&wb[n * 256];
        #pragma unroll
        for (int mf = 0; mf < 4; ++mf)
            af[mf] = *(const short8v*)&hal[abase + (aoffm[mf] + koff) * 8];
        asm volatile("s_waitcnt lgkmcnt(0)" ::: "memory");   // reads complete
        __builtin_amdgcn_sched_barrier(0);
        __builtin_amdgcn_s_barrier();          // barrier1: read-set released
        __builtin_amdgcn_sched_barrier(0);

        // d: restage R0 with H-odd (h-ch 32..63) once X chunks are done
        if (c == 8 && t > 0) {
            const u16* src = hrd + ((size_t)b << 18);
            for (int s = tid; s < 1296; s += 512) {
                int pos = s >> 2, kb = s & 3;
                int hy = pos / 18, hx = pos - hy * 18;
                int gy = y0 + hy - 1, gx = x0 + hx - 1;
                short8v v = (short8v){0,0,0,0,0,0,0,0};
                if ((unsigned)gy < 64u && (unsigned)gx < 64u)
                    v = *(const short8v*)&src[(((gy << 6) + gx) << 6) + 32 + (kb << 3)];
                *(short8v*)&hal[kb * 2592 + pos * 8] = v;
            }
        }
        // e: issue next slab
        if (c + 1 < nck) issue_stage(c + 1, (c + 1) & 1);

        // f: MFMA for chunk c (regs only)
        #pragma unroll
        for (int mf = 0; mf < 4; ++mf)
            #pragma unroll
            for (int n = 0; n < 4; ++n)
                acc[mf][n] = __builtin_amdgcn_mfma_f32_16x16x32_bf16(af[mf], bfr[n], acc[mf][n], 0, 0, 0);

        // g/h: slab(c+1) (+ halo restage) landed, then barrier2
        asm volatile("s_waitcnt lgkmcnt(0) vmcnt(0)" ::: "memory");
        __builtin_amdgcn_sched_barrier(0);
        __builtin_amdgcn_s_barrier();
        __builtin_amdgcn_sched_barrier(0);
    }

    // ---- gates in-register + writeback ----
    float* ob  = out + ((size_t)(b * 10 + t) << 18);
    u16*   hbw = hwr + ((size_t)b << 18);
    #pragma unroll
    for (int mf = 0; mf < 4; ++mf) {
        #pragma unroll
        for (int rr = 0; rr < 4; ++rr) {
            int off = coff[mf][rr];
            float zi = acc[mf][0][rr], zf = acc[mf][1][rr];
            float zg = acc[mf][2][rr], zo = acc[mf][3][rr];
            float cn = sigf(zf) * cpre[mf][rr] + sigf(zi) * tanhf_(zg);
            float hn = sigf(zo) * tanhf_(cn);
            cb[off]  = cn;
            ob[off]  = hn;
            hbw[off] = f2bf(hn);
        }
    }
}

extern "C" void kernel_launch(void* const* d_in, const int* in_sizes, int n_in,
                              void* d_out, int out_size, void* d_ws, size_t ws_size,
                              hipStream_t stream)
{
    const float* x    = (const float*)d_in[0];
    const int*   lbl  = (const int*)  d_in[1];
    const float* kern = (const float*)d_in[2];
    const float* rk   = (const float*)d_in[3];
    const float* bias = (const float*)d_in[4];
    float* out = (float*)d_out;

    // ws: xb 20.97MB | hb0 4.19 | hb1 4.19 | wt_in 0.147 | wt_rk 1.18 | c 8.39
    u16* xb    = (u16*)d_ws;
    u16* hb0   = xb + 10485760;
    u16* hb1   = hb0 + 2097152;
    u16* wt_in = hb1 + 2097152;
    u16* wt_rk = wt_in + 73728;
    float* cst = (float*)(wt_rk + 589824);

    hipLaunchKernelGGL(prep_x, dim3(2048), dim3(256), 0, stream, x, xb);
    hipLaunchKernelGGL(prep_w, dim3(324), dim3(256), 0, stream, kern, rk, wt_in, wt_rk);

    for (int t = 0; t < 10; ++t) {
        const u16* hrd = (t & 1) ? hb0 : hb1;
        u16*       hwr = (t & 1) ? hb1 : hb0;
        hipLaunchKernelGGL(lstm_step, dim3(256), dim3(512), 0, stream,
                           xb, wt_in, wt_rk, bias, lbl, hrd, hwr, cst, out, t);
    }
}

// Round 9
// 243.405 us; speedup vs baseline: 1.4991x; 1.4991x over previous
//
#include <hip/hip_runtime.h>

// ConvLSTM2D MI355X, R9: R3's proven barrier-free K-loop (weights global->regs,
// compiler-pipelined, ONE barrier total) + 16x16 px / 128 co geometry to halve
// per-step L3 weight re-fetch (113 -> 57 MB/step; traffic = 14.5GB / px_per_block).
// B=8,T=10,H=W=64,CIN=32,F=64,4F=256,G=4.
// grid 256 = [b 8][tile 16][fh 2], 512 thr = 8 waves (pxq 4 x wq 2).
// Block = 256 px (16x16) x 128 co (4 gates x 32 f). Wave = 64 px x 64 co,
// acc 4x4 f32x4. LDS: X halo [kb4][324][8] + H halo [kb8][324][8] = 62 KB,
// both staged up front, single __syncthreads. Gates in-register; c f32
// prefetched at kernel top; h bf16 double-buffered ring.

typedef __attribute__((ext_vector_type(8))) short short8v;
typedef __attribute__((ext_vector_type(4))) float f32x4;
typedef unsigned short u16;

__device__ __forceinline__ u16 f2bf(float x) {
    union { float f; unsigned u; } a; a.f = x;
    unsigned r = a.u + 0x7FFFu + ((a.u >> 16) & 1u);   // RNE
    return (u16)(r >> 16);
}
__device__ __forceinline__ float sigf(float x) { return 1.0f / (1.0f + __expf(-x)); }
__device__ __forceinline__ float tanhf_(float x) {
    float e = __expf(2.0f * x);
    return 1.0f - 2.0f / (e + 1.0f);
}

// ---- prep: x f32 -> bf16 ----
__global__ __launch_bounds__(256)
void prep_x(const float* __restrict__ x, u16* __restrict__ xb) {
    size_t i = (size_t)blockIdx.x * 256 + threadIdx.x;
    for (; i < 2621440u; i += (size_t)2048 * 256) {
        float4 v = ((const float4*)x)[i];
        union { u16 u[4]; uint2 q; } o;
        o.u[0] = f2bf(v.x); o.u[1] = f2bf(v.y);
        o.u[2] = f2bf(v.z); o.u[3] = f2bf(v.w);
        ((uint2*)xb)[i] = o.q;
    }
}

// ---- prep: weights -> staged layout ----
// wt_in[tap9][kb4][fh2][n4][fi32][8i], wt_rk[g4][cc18][kb4][fh2][n4][fi32][8i]
// co = n*64 + fh*32 + fi ; k = kb*8+i (X: ci; H: (cc&1)*32 + kb*8+i)
__global__ __launch_bounds__(256)
void prep_w(const float* __restrict__ kern, const float* __restrict__ rk,
            u16* __restrict__ wt_in, u16* __restrict__ wt_rk) {
    int idx = blockIdx.x * 256 + threadIdx.x;
    if (idx >= 82944) return;
    const float* s;
    u16* dst;
    if (idx < 9216) {
        int fi = idx & 31, r1 = idx >> 5;
        int n = r1 & 3, r2 = r1 >> 2;
        int fh = r2 & 1, r3 = r2 >> 1;
        int kb = r3 & 3, tap = r3 >> 2;
        int co = (n << 6) + (fh << 5) + fi;
        s = kern + (size_t)((tap << 5) + (kb << 3)) * 256 + co;
        dst = wt_in + (size_t)idx * 8;
    } else {
        int j = idx - 9216;
        int fi = j & 31, r1 = j >> 5;
        int n = r1 & 3, r2 = r1 >> 2;
        int fh = r2 & 1, r3 = r2 >> 1;
        int kb = r3 & 3, r4 = r3 >> 2;           // 0..71 = g*18+cc
        int g = r4 / 18, cc = r4 - g * 18;
        int tap = cc >> 1;
        int cib = (cc & 1) << 5;
        int co = (n << 6) + (fh << 5) + fi;
        s = rk + (size_t)(((g * 9 + tap) << 6) + cib + (kb << 3)) * 256 + co;
        dst = wt_rk + (size_t)j * 8;
    }
    union { u16 u[8]; uint4 q; } o;
    #pragma unroll
    for (int i = 0; i < 8; ++i) o.u[i] = f2bf(s[i * 256]);
    *(uint4*)dst = o.q;
}

// ---- fused conv + gates, one timestep ----
__global__ __launch_bounds__(512)
void lstm_step(const u16* __restrict__ xb, const u16* __restrict__ wt_in,
               const u16* __restrict__ wt_rk, const float* __restrict__ bias,
               const int* __restrict__ labels, const u16* __restrict__ hrd,
               u16* __restrict__ hwr, float* __restrict__ cst,
               float* __restrict__ out, int t)
{
    // X halo @0: [kb4][324][8] (10368 shorts); H halo @10368: [kb8][324][8]
    __shared__ short hal[31104];   // 62,208 B

    const int tid  = threadIdx.x;
    const int lane = tid & 63;
    const int w    = tid >> 6;
    const int pxq  = w >> 1;                  // 0..3 : 4-row band
    const int wq   = w & 1;                   // 0..1 : 16-f slice
    const int bid  = blockIdx.x;
    const int fh   = bid & 1;
    const int tile = (bid >> 1) & 15;
    const int b    = bid >> 5;
    const int y0 = (tile >> 2) << 4, x0 = (tile & 3) << 4;
    const int g = labels[b];

    const int co_l = lane & 15;
    const int kbl  = lane >> 4;
    const int prow = (lane & 15) >> 3, pcol = lane & 7;
    const int fi = (wq << 4) + co_l;          // 0..31
    const int f  = (fh << 5) + fi;            // 0..63

    float bv[4];
    #pragma unroll
    for (int n = 0; n < 4; ++n)
        bv[n] = bias[(g << 8) + (n << 6) + f];

    // A-frag base positions (18-wide halo): frag mf = (rowpair mf>>1, colhalf mf&1)
    int aoffm[4];
    #pragma unroll
    for (int mf = 0; mf < 4; ++mf)
        aoffm[mf] = ((pxq << 2) + ((mf >> 1) << 1) + prow) * 18 + ((mf & 1) << 3) + pcol;

    // ---- c prefetch + output offsets (16 px per thread) ----
    float* cb = cst + ((size_t)b << 18);
    int coff[4][4];
    float cpre[4][4];
    #pragma unroll
    for (int mf = 0; mf < 4; ++mf)
        #pragma unroll
        for (int rr = 0; rr < 4; ++rr) {
            int pf = (kbl << 2) + rr;         // 0..15 within frag (2x8)
            int yy = y0 + (pxq << 2) + ((mf >> 1) << 1) + (pf >> 3);
            int xx = x0 + ((mf & 1) << 3) + (pf & 7);
            coff[mf][rr] = (((yy << 6) + xx) << 6) + f;
            cpre[mf][rr] = (t > 0) ? cb[coff[mf][rr]] : 0.0f;
        }

    // ---- stage X halo (bf16), 1296 slots ----
    {
        const u16* src = xb + ((size_t)(b * 10 + t) << 17);
        #pragma unroll 2
        for (int s = tid; s < 1296; s += 512) {
            int pos = s >> 2, kb = s & 3;
            int hy = pos / 18, hx = pos - hy * 18;
            int gy = y0 + hy - 1, gx = x0 + hx - 1;
            short8v v = (short8v){0,0,0,0,0,0,0,0};
            if ((unsigned)gy < 64u && (unsigned)gx < 64u)
                v = *(const short8v*)&src[(((gy << 6) + gx) << 5) + (kb << 3)];
            *(short8v*)&hal[kb * 2592 + pos * 8] = v;
        }
    }
    // ---- stage H halo (bf16, all 64 ch), 2592 slots ----
    if (t > 0) {
        const u16* src = hrd + ((size_t)b << 18);
        #pragma unroll 3
        for (int s = tid; s < 2592; s += 512) {
            int pos = s >> 3, kb = s & 7;
            int hy = pos / 18, hx = pos - hy * 18;
            int gy = y0 + hy - 1, gx = x0 + hx - 1;
            short8v v = (short8v){0,0,0,0,0,0,0,0};
            if ((unsigned)gy < 64u && (unsigned)gx < 64u)
                v = *(const short8v*)&src[(((gy << 6) + gx) << 6) + (kb << 3)];
            *(short8v*)&hal[10368 + kb * 2592 + pos * 8] = v;
        }
    }
    __syncthreads();

    f32x4 acc[4][4];
    #pragma unroll
    for (int n = 0; n < 4; ++n)
        #pragma unroll
        for (int mf = 0; mf < 4; ++mf)
            acc[mf][n] = (f32x4){bv[n], bv[n], bv[n], bv[n]};

    // ---- phase X: 9 chunks (weights global->regs, no barriers) ----
    #pragma unroll 3
    for (int tap = 0; tap < 9; ++tap) {
        const int koff = (tap / 3) * 18 + (tap % 3);
        const u16* wb = wt_in + (size_t)((((tap << 2) + kbl) << 1) + fh) * 1024 + fi * 8;
        short8v bfr[4], af[4];
        #pragma unroll
        for (int n = 0; n < 4; ++n)
            bfr[n] = *(const short8v*)&wb[n * 256];
        #pragma unroll
        for (int mf = 0; mf < 4; ++mf)
            af[mf] = *(const short8v*)&hal[kbl * 2592 + (aoffm[mf] + koff) * 8];
        #pragma unroll
        for (int mf = 0; mf < 4; ++mf)
            #pragma unroll
            for (int n = 0; n < 4; ++n)
                acc[mf][n] = __builtin_amdgcn_mfma_f32_16x16x32_bf16(af[mf], bfr[n], acc[mf][n], 0, 0, 0);
    }

    // ---- phase H: 18 chunks ----
    if (t > 0) {
        #pragma unroll 3
        for (int c = 0; c < 18; ++c) {
            const int tap = c >> 1;
            const int koff = (tap / 3) * 18 + (tap % 3);
            const u16* wb = wt_rk + (size_t)(((((g * 18 + c) << 2) + kbl) << 1) + fh) * 1024 + fi * 8;
            short8v bfr[4], af[4];
            #pragma unroll
            for (int n = 0; n < 4; ++n)
                bfr[n] = *(const short8v*)&wb[n * 256];
            const int abase = 10368 + (((c & 1) << 2) + kbl) * 2592;
            #pragma unroll
            for (int mf = 0; mf < 4; ++mf)
                af[mf] = *(const short8v*)&hal[abase + (aoffm[mf] + koff) * 8];
            #pragma unroll
            for (int mf = 0; mf < 4; ++mf)
                #pragma unroll
                for (int n = 0; n < 4; ++n)
                    acc[mf][n] = __builtin_amdgcn_mfma_f32_16x16x32_bf16(af[mf], bfr[n], acc[mf][n], 0, 0, 0);
        }
    }

    // ---- gates in-register + writeback ----
    float* ob  = out + ((size_t)(b * 10 + t) << 18);
    u16*   hbw = hwr + ((size_t)b << 18);
    #pragma unroll
    for (int mf = 0; mf < 4; ++mf) {
        #pragma unroll
        for (int rr = 0; rr < 4; ++rr) {
            int off = coff[mf][rr];
            float zi = acc[mf][0][rr], zf = acc[mf][1][rr];
            float zg = acc[mf][2][rr], zo = acc[mf][3][rr];
            float cn = sigf(zf) * cpre[mf][rr] + sigf(zi) * tanhf_(zg);
            float hn = sigf(zo) * tanhf_(cn);
            cb[off]  = cn;
            ob[off]  = hn;
            hbw[off] = f2bf(hn);
        }
    }
}

extern "C" void kernel_launch(void* const* d_in, const int* in_sizes, int n_in,
                              void* d_out, int out_size, void* d_ws, size_t ws_size,
                              hipStream_t stream)
{
    const float* x    = (const float*)d_in[0];
    const int*   lbl  = (const int*)  d_in[1];
    const float* kern = (const float*)d_in[2];
    const float* rk   = (const float*)d_in[3];
    const float* bias = (const float*)d_in[4];
    float* out = (float*)d_out;

    // ws: xb 20.97MB | hb0 4.19 | hb1 4.19 | wt_in 0.147 | wt_rk 1.18 | c 8.39
    u16* xb    = (u16*)d_ws;
    u16* hb0   = xb + 10485760;
    u16* hb1   = hb0 + 2097152;
    u16* wt_in = hb1 + 2097152;
    u16* wt_rk = wt_in + 73728;
    float* cst = (float*)(wt_rk + 589824);

    hipLaunchKernelGGL(prep_x, dim3(2048), dim3(256), 0, stream, x, xb);
    hipLaunchKernelGGL(prep_w, dim3(324), dim3(256), 0, stream, kern, rk, wt_in, wt_rk);

    for (int t = 0; t < 10; ++t) {
        const u16* hrd = (t & 1) ? hb0 : hb1;
        u16*       hwr = (t & 1) ? hb1 : hb0;
        hipLaunchKernelGGL(lstm_step, dim3(256), dim3(512), 0, stream,
                           xb, wt_in, wt_rk, bias, lbl, hrd, hwr, cst, out, t);
    }
}